// Round 6
// baseline (386.654 us; speedup 1.0000x reference)
//
#include <hip/hip_runtime.h>
#include <cstdint>
#include <cstddef>

// GCN: h1 = relu(Â (x W1) + b1); h2 = relu(Â (h1 W2) + b2);
// g = mean-pool(h2 by batch); out = log_softmax(relu(g Wl1 + bl1) Wl2 + bl2)
// Â = D^-1/2 (A + I) D^-1/2.
//
// R6: R5's in-gather fused matvec cost 128 LDS reads + 64 FMA per node
// (gather 66->99us). De-fused: gather is pure (no LDS, 4-deep unrolled
// quarter-wave row loads for MLP, relu'd bf16 out); layer-2 dense is a
// separate bf16-in/bf16-out GEMM (LDS-tiled, 64x reuse).

#define HF 64          // feature width
#define BSH 9          // bucket shift: 512 nodes per bucket
#define BSZ 512
#define PCHUNK 8192    // edges per k_part block
#define CAP 12288      // LDS out capacity in k_place2

typedef unsigned u32;

__device__ __forceinline__ unsigned short f2bf(float x) {
    unsigned u = __float_as_uint(x);
    unsigned r = (u + 0x7fffu + ((u >> 16) & 1u)) >> 16;   // RNE
    return (unsigned short)r;
}
__device__ __forceinline__ float bfl(u32 w) { return __uint_as_float(w << 16); }
__device__ __forceinline__ float bfh(u32 w) { return __uint_as_float(w & 0xffff0000u); }
__device__ __forceinline__ float bf2f(unsigned short s) { return __uint_as_float(((u32)s) << 16); }

// ---- generic zero ----------------------------------------------------------
__global__ __launch_bounds__(256) void k_zero(u32* __restrict__ p, int n) {
    int i = blockIdx.x * 256 + threadIdx.x;
    if (i < n) p[i] = 0u;
}

// ---- coarse bucket histogram (bucket = col >> BSH) -------------------------
__global__ __launch_bounds__(256) void k_bhist(const int* __restrict__ cols,
                                               u32* __restrict__ gbh, int E, int NB) {
    __shared__ u32 h[256];
    int tid = threadIdx.x;
    h[tid] = 0;
    __syncthreads();
    for (int i = blockIdx.x * 256 + tid; i < E; i += gridDim.x * 256)
        atomicAdd(&h[((u32)cols[i]) >> BSH], 1u);
    __syncthreads();
    if (tid < NB && h[tid]) atomicAdd(&gbh[tid], h[tid]);
}

// ---- bucket scan (one block; NB <= 256) ------------------------------------
__global__ __launch_bounds__(256) void k_bscan(const u32* __restrict__ gbh,
                                               u32* __restrict__ bscan,
                                               u32* __restrict__ gcurb, int NB, int E) {
    __shared__ u32 s[256];
    int tid = threadIdx.x;
    u32 v = (tid < NB) ? gbh[tid] : 0u;
    s[tid] = v;
    __syncthreads();
    for (int o = 1; o < 256; o <<= 1) {
        u32 t = (tid >= o) ? s[tid - o] : 0u;
        __syncthreads();
        s[tid] += t;
        __syncthreads();
    }
    u32 excl = s[tid] - v;
    if (tid < NB) { bscan[tid] = excl; gcurb[tid] = excl; }
    if (tid == 0) bscan[NB] = (u32)E;
}

// ---- partition: edges -> part[] grouped by coarse bucket, LDS-reordered ----
// part element packs (col & 511) << 17 | row  (N < 2^17).
__global__ __launch_bounds__(256) void k_part(const int* __restrict__ rows,
                                              const int* __restrict__ cols,
                                              u32* __restrict__ gcurb,
                                              u32* __restrict__ part, int E) {
    __shared__ u32 hist[256];
    __shared__ u32 off[256];
    __shared__ u32 obase[256];
    __shared__ u32 cur[256];
    __shared__ u32 sc[256];
    __shared__ u32 stage[PCHUNK];
    __shared__ unsigned char sbk[PCHUNK];
    const int tid = threadIdx.x;
    const int e0  = blockIdx.x * PCHUNK;
    u32 er[32], ec[32];

    hist[tid] = 0;
    __syncthreads();
#pragma unroll
    for (int j = 0; j < 32; ++j) {
        int e = e0 + j * 256 + tid;
        if (e < E) {
            ec[j] = (u32)cols[e];
            er[j] = (u32)rows[e];
            atomicAdd(&hist[ec[j] >> BSH], 1u);
        } else ec[j] = 0xFFFFFFFFu;
    }
    __syncthreads();
    u32 v = hist[tid];
    sc[tid] = v;
    __syncthreads();
    for (int o = 1; o < 256; o <<= 1) {
        u32 t = (tid >= o) ? sc[tid - o] : 0u;
        __syncthreads();
        sc[tid] += t;
        __syncthreads();
    }
    off[tid] = sc[tid] - v;
    cur[tid] = sc[tid] - v;
    obase[tid] = v ? atomicAdd(&gcurb[tid], v) : 0u;
    __syncthreads();
#pragma unroll
    for (int j = 0; j < 32; ++j) {
        if (ec[j] != 0xFFFFFFFFu) {
            u32 bk  = ec[j] >> BSH;
            u32 pos = atomicAdd(&cur[bk], 1u);
            stage[pos] = ((ec[j] & (BSZ - 1)) << 17) | er[j];
            sbk[pos]   = (unsigned char)bk;
        }
    }
    __syncthreads();
    const int total = (e0 + PCHUNK <= E) ? PCHUNK : (E - e0);
    for (int i = tid; i < total; i += 256) {
        u32 bk = sbk[i];
        part[obase[bk] + ((u32)i - off[bk])] = stage[i];
    }
}

// ---- per-bucket placement: node hist + scan + dis + rowptr + eidx in LDS ---
__global__ __launch_bounds__(256) void k_place2(const u32* __restrict__ bscan,
                                                const u32* __restrict__ part,
                                                u32* __restrict__ rowptr,
                                                float* __restrict__ dis,
                                                int* __restrict__ eidx, int N) {
    __shared__ u32 cnt_[512];
    __shared__ u32 off_[513];
    __shared__ u32 sc[256];
    __shared__ u32 cur[512];
    __shared__ u32 outb[CAP];
    const int tid = threadIdx.x;
    const int b   = blockIdx.x;
    const int n0  = b << BSH;
    const u32 base = bscan[b];
    const u32 cntB = bscan[b + 1] - base;

    cnt_[tid] = 0; cnt_[tid + 256] = 0;
    __syncthreads();
    for (u32 i = tid; i < cntB; i += 256)
        atomicAdd(&cnt_[part[base + i] >> 17], 1u);
    __syncthreads();
    u32 c0 = cnt_[2 * tid], c1 = cnt_[2 * tid + 1];
    u32 s = c0 + c1;
    sc[tid] = s;
    __syncthreads();
    for (int o = 1; o < 256; o <<= 1) {
        u32 t = (tid >= o) ? sc[tid - o] : 0u;
        __syncthreads();
        sc[tid] += t;
        __syncthreads();
    }
    u32 ex = sc[tid] - s;
    off_[2 * tid] = ex;          cur[2 * tid] = ex;
    off_[2 * tid + 1] = ex + c0; cur[2 * tid + 1] = ex + c0;
    if (tid == 0) off_[512] = cntB;
    __syncthreads();
    for (int j = tid; j < 512; j += 256) {
        int n = n0 + j;
        if (n < N) {
            rowptr[n] = base + off_[j];
            dis[n]    = rsqrtf(1.0f + (float)cnt_[j]);
        }
    }
    if (cntB <= CAP) {
        for (u32 i = tid; i < cntB; i += 256) {
            u32 p   = part[base + i];
            u32 pos = atomicAdd(&cur[p >> 17], 1u);
            outb[pos] = p & 0x1FFFFu;
        }
        __syncthreads();
        for (u32 i = tid; i < cntB; i += 256)
            eidx[base + i] = (int)outb[i];
    } else {
        int j0 = 0;
        while (j0 < 512) {
            int j1 = j0 + 1;
            while (j1 < 512 && off_[j1 + 1] - off_[j0] <= CAP) ++j1;
            u32 p0 = off_[j0], p1 = off_[j1];
            for (u32 i = tid; i < cntB; i += 256) {
                u32 p  = part[base + i];
                u32 lc = p >> 17;
                if (lc >= (u32)j0 && lc < (u32)j1) {
                    u32 pos = atomicAdd(&cur[lc], 1u);
                    outb[pos - p0] = p & 0x1FFFFu;
                }
            }
            __syncthreads();
            for (u32 i = tid; i < p1 - p0; i += 256)
                eidx[base + p0 + i] = (int)outb[i];
            __syncthreads();
            j0 = j1;
        }
    }
}

// ---- dense transform: HS[N,64](bf16) = dis[n] * (X[N,64] @ W[64,64]) -------
// BF16IN=0: X fp32; BF16IN=1: X bf16 (already relu'd upstream).
template <int BF16IN>
__global__ __launch_bounds__(256) void k_gemm(const void* __restrict__ Xv,
                                              const float* __restrict__ W,
                                              const float* __restrict__ dis,
                                              unsigned short* __restrict__ HS, int N) {
    __shared__ float ws[64 * 64];
    __shared__ float xs[64 * 68];
    const int tid  = threadIdx.x;
    const int row0 = blockIdx.x * 64;

#pragma unroll
    for (int i = 0; i < 4; ++i) {
        int idx4 = i * 256 + tid;
        *(float4*)&ws[idx4 * 4] = ((const float4*)W)[idx4];
    }
#pragma unroll
    for (int i = 0; i < 4; ++i) {
        int idx4 = i * 256 + tid;
        int r    = idx4 >> 4;
        int kk   = (idx4 & 15) << 2;
        float4 v = float4{0.f, 0.f, 0.f, 0.f};
        int row  = row0 + r;
        if (row < N) {
            if (BF16IN) {
                const unsigned short* Xb = (const unsigned short*)Xv;
                ushort4 pk = ((const ushort4*)(Xb + (size_t)row * HF))[idx4 & 15];
                v.x = bf2f(pk.x); v.y = bf2f(pk.y);
                v.z = bf2f(pk.z); v.w = bf2f(pk.w);
            } else {
                v = ((const float4*)((const float*)Xv + (size_t)row * HF))[idx4 & 15];
            }
        }
        *(float4*)&xs[r * 68 + kk] = v;
    }
    __syncthreads();

    const int rg = tid >> 4;
    const int cg = tid & 15;
    float4 a0 = float4{0.f, 0.f, 0.f, 0.f};
    float4 a1 = a0, a2 = a0, a3 = a0;

#pragma unroll
    for (int k = 0; k < 64; ++k) {
        float4 wv = *(float4*)&ws[k * 64 + cg * 4];
        float  x0 = xs[(rg * 4 + 0) * 68 + k];
        float  x1 = xs[(rg * 4 + 1) * 68 + k];
        float  x2 = xs[(rg * 4 + 2) * 68 + k];
        float  x3 = xs[(rg * 4 + 3) * 68 + k];
        a0.x += x0 * wv.x; a0.y += x0 * wv.y; a0.z += x0 * wv.z; a0.w += x0 * wv.w;
        a1.x += x1 * wv.x; a1.y += x1 * wv.y; a1.z += x1 * wv.z; a1.w += x1 * wv.w;
        a2.x += x2 * wv.x; a2.y += x2 * wv.y; a2.z += x2 * wv.z; a2.w += x2 * wv.w;
        a3.x += x3 * wv.x; a3.y += x3 * wv.y; a3.z += x3 * wv.z; a3.w += x3 * wv.w;
    }

    float4 accs[4] = {a0, a1, a2, a3};
#pragma unroll
    for (int j = 0; j < 4; ++j) {
        int row = row0 + rg * 4 + j;
        if (row < N) {
            float d = dis[row];
            float4 a = accs[j];
            ushort4 pk;
            pk.x = f2bf(d * a.x); pk.y = f2bf(d * a.y);
            pk.z = f2bf(d * a.z); pk.w = f2bf(d * a.w);
            *(ushort4*)&HS[(size_t)row * HF + cg * 4] = pk;
        }
    }
}

// ---- CSR gather: out = relu( dis[n]*(sum_{r in nbrs(n)} hs[r] + hs[n]) + b )
// bf16 out. One wave per node; 4 quarter-waves each load a full 128B bf16 row;
// 4-deep unroll -> up to 16 rows in flight per wave.
__global__ __launch_bounds__(256) void k_gather(const u32* __restrict__ rowptr,
                                                const int* __restrict__ eidx,
                                                const float* __restrict__ dis,
                                                const u32* __restrict__ hs,   // bf16 pairs
                                                const float* __restrict__ bvec,
                                                unsigned short* __restrict__ outbf,
                                                int N, int E) {
    const int tid  = threadIdx.x;
    const int wv   = tid >> 6;
    const int lane = tid & 63;
    const int q    = lane >> 4;      // quarter 0..3
    const int f4   = lane & 15;      // feature quad: feats 4*f4 .. 4*f4+3
    const int n    = blockIdx.x * 4 + wv;
    if (n >= N) return;

    u32 start = rowptr[n];
    u32 end   = (n + 1 < N) ? rowptr[n + 1] : (u32)E;
    float dn  = dis[n];
    float4 acc = float4{0.f, 0.f, 0.f, 0.f};

    u32 e = start + q;
    for (; e + 12 < end; e += 16) {          // 4 edges per quarter per iter
        int r0 = eidx[e], r1 = eidx[e + 4], r2 = eidx[e + 8], r3 = eidx[e + 12];
        uint2 w0 = ((const uint2*)(hs + (size_t)r0 * 32))[f4];
        uint2 w1 = ((const uint2*)(hs + (size_t)r1 * 32))[f4];
        uint2 w2 = ((const uint2*)(hs + (size_t)r2 * 32))[f4];
        uint2 w3 = ((const uint2*)(hs + (size_t)r3 * 32))[f4];
        acc.x += (bfl(w0.x) + bfl(w1.x)) + (bfl(w2.x) + bfl(w3.x));
        acc.y += (bfh(w0.x) + bfh(w1.x)) + (bfh(w2.x) + bfh(w3.x));
        acc.z += (bfl(w0.y) + bfl(w1.y)) + (bfl(w2.y) + bfl(w3.y));
        acc.w += (bfh(w0.y) + bfh(w1.y)) + (bfh(w2.y) + bfh(w3.y));
    }
    for (; e < end; e += 4) {
        int r = eidx[e];
        uint2 w = ((const uint2*)(hs + (size_t)r * 32))[f4];
        acc.x += bfl(w.x); acc.y += bfh(w.x);
        acc.z += bfl(w.y); acc.w += bfh(w.y);
    }
    if (q == 0) {                            // self-loop
        uint2 w = ((const uint2*)(hs + (size_t)n * 32))[f4];
        acc.x += bfl(w.x); acc.y += bfh(w.x);
        acc.z += bfl(w.y); acc.w += bfh(w.y);
    }
    // reduce across the 4 quarters
    acc.x += __shfl_xor(acc.x, 32); acc.y += __shfl_xor(acc.y, 32);
    acc.z += __shfl_xor(acc.z, 32); acc.w += __shfl_xor(acc.w, 32);
    acc.x += __shfl_xor(acc.x, 16); acc.y += __shfl_xor(acc.y, 16);
    acc.z += __shfl_xor(acc.z, 16); acc.w += __shfl_xor(acc.w, 16);

    if (q == 0) {
        float4 bv = ((const float4*)bvec)[f4];
        ushort4 pk;
        pk.x = f2bf(fmaxf(dn * acc.x + bv.x, 0.f));
        pk.y = f2bf(fmaxf(dn * acc.y + bv.y, 0.f));
        pk.z = f2bf(fmaxf(dn * acc.z + bv.z, 0.f));
        pk.w = f2bf(fmaxf(dn * acc.w + bv.w, 0.f));
        *(ushort4*)&outbf[(size_t)n * HF + f4 * 4] = pk;
    }
}

// ---- pooling: one block per graph (batch sorted), bf16 in, no atomics ------
__device__ __forceinline__ int lower_bound(const int* __restrict__ a, int n, int key) {
    int lo = 0, hi = n;
    while (lo < hi) { int mid = (lo + hi) >> 1; if (a[mid] < key) lo = mid + 1; else hi = mid; }
    return lo;
}

__global__ __launch_bounds__(256) void k_pool(const u32* __restrict__ aggR,  // bf16 pairs
                                              const int* __restrict__ batch,
                                              float* __restrict__ gmean, int N) {
    __shared__ float red[4][64];
    const int g    = blockIdx.x;
    const int lane = threadIdx.x & 63;
    const int w    = threadIdx.x >> 6;
    int s = lower_bound(batch, N, g);
    int e = lower_bound(batch, N, g + 1);
    float acc = 0.f;
    for (int n = s + w; n < e; n += 4) {
        u32 wv = aggR[(size_t)n * 32 + (lane >> 1)];
        acc += (lane & 1) ? bfh(wv) : bfl(wv);
    }
    red[w][lane] = acc;
    __syncthreads();
    if (w == 0) {
        float t = red[0][lane] + red[1][lane] + red[2][lane] + red[3][lane];
        gmean[g * HF + lane] = t / fmaxf((float)(e - s), 1.0f);
    }
}

// ---- fused MLP head (one block; thread = graph) ----------------------------
__global__ __launch_bounds__(256) void k_head(const float* __restrict__ gmean,
                                              const float* __restrict__ Wl1,
                                              const float* __restrict__ bl1,
                                              const float* __restrict__ Wl2,
                                              const float* __restrict__ bl2,
                                              float* __restrict__ out) {
    __shared__ float w1[64 * 32];
    __shared__ float w2[64];
    __shared__ float bb1[32];
    const int tid = threadIdx.x;
    for (int i = tid; i < 64 * 32; i += 256) w1[i] = Wl1[i];
    if (tid < 64) w2[tid] = Wl2[tid];
    if (tid < 32) bb1[tid] = bl1[tid];
    __syncthreads();

    const int g = tid;  // 256 graphs
    float gm[64];
#pragma unroll
    for (int k = 0; k < 64; ++k) gm[k] = gmean[g * HF + k];
    float l0 = bl2[0], l1 = bl2[1];
#pragma unroll
    for (int j = 0; j < 32; ++j) {
        float a = bb1[j];
#pragma unroll
        for (int k = 0; k < 64; ++k) a += gm[k] * w1[k * 32 + j];
        a = fmaxf(a, 0.f);
        l0 += a * w2[2 * j];
        l1 += a * w2[2 * j + 1];
    }
    float m   = fmaxf(l0, l1);
    float lse = m + logf(expf(l0 - m) + expf(l1 - m));
    out[2 * g]     = l0 - lse;
    out[2 * g + 1] = l1 - lse;
}

// ---- driver ----------------------------------------------------------------
extern "C" void kernel_launch(void* const* d_in, const int* in_sizes, int n_in,
                              void* d_out, int out_size, void* d_ws, size_t ws_size,
                              hipStream_t stream) {
    const float* x   = (const float*)d_in[0];
    const int*   ei  = (const int*)d_in[1];
    const int*   bi  = (const int*)d_in[2];
    const float* W1  = (const float*)d_in[3];
    const float* b1  = (const float*)d_in[4];
    const float* W2  = (const float*)d_in[5];
    const float* b2  = (const float*)d_in[6];
    const float* Wl1 = (const float*)d_in[7];
    const float* bl1 = (const float*)d_in[8];
    const float* Wl2 = (const float*)d_in[9];
    const float* bl2 = (const float*)d_in[10];
    float* out = (float*)d_out;

    const int N = in_sizes[0] / HF;
    const int E = in_sizes[1] / 2;
    const int* rows = ei;
    const int* cols = ei + E;
    const int NB = (N + BSZ - 1) / BSZ;

    // workspace (4B units). Two N*64 bf16 regions ping-pong:
    //   region A: part (dead after place2) -> hs1 -> hs2 (gemm2 out)
    //   region B: agg1R (gather1 out) -> aggR (gather2 out)
    float* ws = (float*)d_ws;
    size_t o = 0;
    float* dis    = ws + o; o += ((size_t)N + 63) / 64 * 64;
    unsigned short* regA = (unsigned short*)(ws + o); o += (size_t)N * 32;  // bf16 N x 64
    unsigned short* regB = (unsigned short*)(ws + o); o += (size_t)N * 32;  // bf16 N x 64
    u32*   part   = (u32*)regA;
    u32*   rowptr = (u32*)(ws + o); o += ((size_t)N + 63) / 64 * 64;
    int*   eidx   = (int*)(ws + o); o += (size_t)E;
    u32*   gbh    = (u32*)(ws + o); o += 256;
    u32*   bscan  = (u32*)(ws + o); o += 320;
    u32*   gcurb  = (u32*)(ws + o); o += 256;
    float* gmean  = ws + o; o += 256 * HF;

    const int gb = (N + 63) / 64;

    // CSR build (two-level bucket sort; shared by both layers)
    k_zero<<<1, 256, 0, stream>>>(gbh, 256);
    k_bhist<<<256, 256, 0, stream>>>(cols, gbh, E, NB);
    k_bscan<<<1, 256, 0, stream>>>(gbh, bscan, gcurb, NB, E);
    k_part<<<(E + PCHUNK - 1) / PCHUNK, 256, 0, stream>>>(rows, cols, gcurb, part, E);
    k_place2<<<NB, 256, 0, stream>>>(bscan, part, rowptr, dis, eidx, N);

    // layer 1: hs1 = dis*(x@W1)  [regA];  agg1R = relu(gather(hs1)+b1) [regB]
    k_gemm<0><<<gb, 256, 0, stream>>>(x, W1, dis, regA, N);
    k_gather<<<(N + 3) / 4, 256, 0, stream>>>(rowptr, eidx, dis, (const u32*)regA,
                                              b1, regB, N, E);
    // layer 2: hs2 = dis*(agg1R@W2) [regA];  aggR = relu(gather(hs2)+b2) [regB]
    k_gemm<1><<<gb, 256, 0, stream>>>(regB, W2, dis, regA, N);
    k_gather<<<(N + 3) / 4, 256, 0, stream>>>(rowptr, eidx, dis, (const u32*)regA,
                                              b2, regB, N, E);

    // mean pool + fused head
    k_pool<<<256, 256, 0, stream>>>((const u32*)regB, bi, gmean, N);
    k_head<<<1, 256, 0, stream>>>(gmean, Wl1, bl1, Wl2, bl2, out);
}